// Round 10
// baseline (466.220 us; speedup 1.0000x reference)
//
#include <hip/hip_runtime.h>
#include <hip/hip_bf16.h>
#include <hip/hip_fp8.h>

#define N_NODES 100000
#define NPAD    100096          // 782 * 128
#define N_EDGES 1600000
#define BATCH   256
#define HDIM    512

typedef unsigned short u16;
typedef unsigned char  u8;
typedef __attribute__((ext_vector_type(8))) short bf16x8;
typedef __attribute__((ext_vector_type(8))) unsigned short u16x8;
typedef __attribute__((ext_vector_type(16))) unsigned char u8x16;
typedef __attribute__((ext_vector_type(4))) float f32x4;

__device__ __forceinline__ float bf2f(u16 u) {
    union { unsigned i; float f; } v; v.i = ((unsigned)u) << 16; return v.f;
}
__device__ __forceinline__ u16 f2bf(float f) {
    __hip_bfloat16 h = __float2bfloat16(f);
    return *reinterpret_cast<u16*>(&h);
}
__device__ __forceinline__ u8 f2fp8(float f) {
    __hip_fp8_e4m3 q(f); return (u8)q.__x;
}
__device__ __forceinline__ float fp82f(u8 b) {
    __hip_fp8_e4m3 q; q.__x = (__hip_fp8_storage_t)b; return (float)q;
}

// ============ MFMA GEMM (node path): C = act(A[M,K]@W) , K<=128, 1 stage =====
// A: [M][K] bf16. Wt: [N][K] bf16. 128x128 tile, 4 waves 2x2, 4x4 frags of
// 16x16x32. LDS via global_load_lds w=16, pre-swizzled source (rule 21).
// ACT: 0 none, 2 elu. SCALE: dis[row]. F8: store e4m3 fp8 (else bf16).
template<int K, int ACT, int SCALE, int F8>
__global__ __launch_bounds__(256) void gemm_mfma(
        const u16* __restrict__ A, const u16* __restrict__ Wt,
        const float* __restrict__ bias, const float* __restrict__ dis,
        void* __restrict__ Cv, int N) {
    constexpr int RB = K * 2;                 // row bytes
    __shared__ u16 As[128 * K];
    __shared__ u16 Bs[128 * K];
    const int tid  = threadIdx.x;
    const int lane = tid & 63;
    const int w    = tid >> 6;
    const int wr   = w >> 1, wc = w & 1;
    const int row0 = blockIdx.y * 128;
    const int col0 = blockIdx.x * 128;

    constexpr int WB     = 128 * RB / 4;
    constexpr int PASSES = WB / 1024;
    const size_t Abase = (size_t)row0 * K;
    const size_t Bbase = (size_t)col0 * K;
    #pragma unroll
    for (int p = 0; p < PASSES; ++p) {
        int Lb  = w * WB + p * 1024;
        int L   = Lb + lane * 16;
        int row = L / RB;
        int cb  = L % RB;
        int scb = cb ^ ((row & 7) << 4);
        const u16* ga = A  + Abase + (size_t)row * K + (scb >> 1);
        const u16* gb = Wt + Bbase + (size_t)row * K + (scb >> 1);
        __builtin_amdgcn_global_load_lds((const __attribute__((address_space(1))) void*)ga,
            (__attribute__((address_space(3))) void*)&As[Lb >> 1], 16, 0, 0);
        __builtin_amdgcn_global_load_lds((const __attribute__((address_space(1))) void*)gb,
            (__attribute__((address_space(3))) void*)&Bs[Lb >> 1], 16, 0, 0);
    }
    asm volatile("s_waitcnt vmcnt(0)" ::: "memory");
    __syncthreads();

    const int rl = lane & 15;
    const int kg = lane >> 4;
    f32x4 acc[4][4] = {};
    #pragma unroll
    for (int s = 0; s < K / 32; ++s) {
        bf16x8 af[4], bg[4];
        #pragma unroll
        for (int m = 0; m < 4; ++m) {
            int row = wr * 64 + m * 16 + rl;
            int cb  = s * 64 + kg * 16;
            int scb = cb ^ ((row & 7) << 4);
            af[m] = *(const bf16x8*)&As[(row * RB + scb) >> 1];
        }
        #pragma unroll
        for (int n = 0; n < 4; ++n) {
            int row = wc * 64 + n * 16 + rl;
            int cb  = s * 64 + kg * 16;
            int scb = cb ^ ((row & 7) << 4);
            bg[n] = *(const bf16x8*)&Bs[(row * RB + scb) >> 1];
        }
        #pragma unroll
        for (int m = 0; m < 4; ++m)
            #pragma unroll
            for (int n = 0; n < 4; ++n)
                acc[m][n] = __builtin_amdgcn_mfma_f32_16x16x32_bf16(af[m], bg[n], acc[m][n], 0, 0, 0);
    }

    #pragma unroll
    for (int m = 0; m < 4; ++m) {
        #pragma unroll
        for (int r = 0; r < 4; ++r) {
            int grow = row0 + wr * 64 + m * 16 + kg * 4 + r;
            float ds = SCALE ? dis[grow] : 1.f;
            #pragma unroll
            for (int n = 0; n < 4; ++n) {
                int gcol = col0 + wc * 64 + n * 16 + rl;
                float v = acc[m][n][r] + bias[gcol];
                if (ACT == 2) v = v > 0.f ? v : expm1f(v);
                v *= ds;
                if (F8) ((u8*)Cv)[(size_t)grow * N + gcol] = f2fp8(v);
                else    ((u16*)Cv)[(size_t)grow * N + gcol] = f2bf(v);
            }
        }
    }
}

// ======== MFMA GEMM (front-end): 64x64 tile, K-loop BK=64, runtime lda/ldc ==
template<int ACT>
__global__ __launch_bounds__(256) void gemm64(
        const u16* __restrict__ A, const u16* __restrict__ Wt,
        const float* __restrict__ bias, u16* __restrict__ C,
        int K, int lda, int ldc) {
    __shared__ u16 As[64 * 64];
    __shared__ u16 Bs[64 * 64];
    const int tid  = threadIdx.x;
    const int lane = tid & 63;
    const int w    = tid >> 6;
    const int wr   = w >> 1, wc = w & 1;
    const int row0 = blockIdx.y * 64;
    const int col0 = blockIdx.x * 64;
    const int rl = lane & 15;
    const int kg = lane >> 4;
    f32x4 acc[2][2] = {};

    for (int k0 = 0; k0 < K; k0 += 64) {
        #pragma unroll
        for (int p = 0; p < 2; ++p) {
            int Lb  = w * 2048 + p * 1024;
            int L   = Lb + lane * 16;
            int row = L >> 7;
            int cb  = L & 127;
            int scb = cb ^ ((row & 7) << 4);
            const u16* ga = A  + (size_t)(row0 + row) * lda + k0 + (scb >> 1);
            const u16* gb = Wt + (size_t)(col0 + row) * K   + k0 + (scb >> 1);
            __builtin_amdgcn_global_load_lds((const __attribute__((address_space(1))) void*)ga,
                (__attribute__((address_space(3))) void*)&As[Lb >> 1], 16, 0, 0);
            __builtin_amdgcn_global_load_lds((const __attribute__((address_space(1))) void*)gb,
                (__attribute__((address_space(3))) void*)&Bs[Lb >> 1], 16, 0, 0);
        }
        asm volatile("s_waitcnt vmcnt(0)" ::: "memory");
        __syncthreads();
        #pragma unroll
        for (int s = 0; s < 2; ++s) {
            bf16x8 af[2], bg[2];
            #pragma unroll
            for (int m = 0; m < 2; ++m) {
                int row = wr * 32 + m * 16 + rl;
                int cb  = s * 64 + kg * 16;
                int scb = cb ^ ((row & 7) << 4);
                af[m] = *(const bf16x8*)&As[(row * 128 + scb) >> 1];
            }
            #pragma unroll
            for (int n = 0; n < 2; ++n) {
                int row = wc * 32 + n * 16 + rl;
                int cb  = s * 64 + kg * 16;
                int scb = cb ^ ((row & 7) << 4);
                bg[n] = *(const bf16x8*)&Bs[(row * 128 + scb) >> 1];
            }
            #pragma unroll
            for (int m = 0; m < 2; ++m)
                #pragma unroll
                for (int n = 0; n < 2; ++n)
                    acc[m][n] = __builtin_amdgcn_mfma_f32_16x16x32_bf16(af[m], bg[n], acc[m][n], 0, 0, 0);
        }
        __syncthreads();
    }

    #pragma unroll
    for (int m = 0; m < 2; ++m) {
        #pragma unroll
        for (int r = 0; r < 4; ++r) {
            int grow = row0 + wr * 32 + m * 16 + kg * 4 + r;
            #pragma unroll
            for (int n = 0; n < 2; ++n) {
                int gcol = col0 + wc * 32 + n * 16 + rl;
                float v = acc[m][n][r] + bias[gcol];
                if (ACT == 1) v = fmaxf(v, 0.f);
                C[(size_t)grow * ldc + gcol] = f2bf(v);
            }
        }
    }
}

// ===== fused prep+deg: histogram/slot pass AND weight transposes + video ====
template<int K, int N>
__device__ __forceinline__ void tw(const float* __restrict__ W, u16* __restrict__ Wt, int t) {
    int n = t / K, k = t - n * K;
    Wt[t] = f2bf(W[(size_t)k * N + n]);
}

#define DEG_BLKS 6250   // 6250*256 = 1.6M edges

__global__ void prep_deg(const int* __restrict__ dstE, int* __restrict__ deg,
                         int* __restrict__ slot,
                         const float* __restrict__ G1W, u16* __restrict__ g1wt,
                         const float* __restrict__ G2W, u16* __restrict__ g2wt,
                         const float* __restrict__ Wv,  u16* __restrict__ WvT,
                         const float* __restrict__ Wva, u16* __restrict__ WvaT,
                         const float* __restrict__ Wo,  u16* __restrict__ WoT,
                         const float* __restrict__ Wf,  u16* __restrict__ WfT,
                         const float* __restrict__ video, u16* __restrict__ vidbf) {
    int bid = blockIdx.x;
    const int tid = threadIdx.x;
    if (bid < DEG_BLKS) {
        int e = bid * 256 + tid;
        slot[e] = atomicAdd(&deg[dstE[e]], 1);
        return;
    }
    bid -= DEG_BLKS;
    if (bid < 32)        { tw<64, 128>  (G1W, g1wt, bid * 256 + tid); }
    else if (bid < 96)   { tw<128, 128> (G2W, g2wt, (bid - 32) * 256 + tid); }
    else if (bid < 1120) { tw<512, 512> (Wv,  WvT,  (bid - 96) * 256 + tid); }
    else if (bid < 2144) { tw<512, 512> (Wva, WvaT, (bid - 1120) * 256 + tid); }
    else if (bid < 3168) { tw<512, 512> (Wo,  WoT,  (bid - 2144) * 256 + tid); }
    else if (bid < 5216) { tw<1024, 512>(Wf,  WfT,  (bid - 3168) * 256 + tid); }
    else { int t = (bid - 5216) * 256 + tid; vidbf[t] = f2bf(video[t]); }
}

// == fused tail: pooled256 = (pool/cnt)@G3W+b3; final = relu([f|p]@Wff); heads
__global__ void final_fused(const u16* __restrict__ fusedb,
                            const float* __restrict__ pooled, const float* __restrict__ counts,
                            const float* __restrict__ G3W, const float* __restrict__ G3b,
                            const float* __restrict__ Wff, const float* __restrict__ bff,
                            const float* __restrict__ Wb,  const float* __restrict__ bb,
                            const float* __restrict__ Wa,  const float* __restrict__ ba,
                            float* __restrict__ out) {
    __shared__ float cat[768], fin[512], pp[128];
    __shared__ float rd[4][4];
    const int b = blockIdx.x, tid = threadIdx.x;
    cat[tid] = bf2f(fusedb[b * 512 + tid]);
    cat[tid + 256] = bf2f(fusedb[b * 512 + 256 + tid]);
    float inv = 1.f / counts[b];
    if (tid < 128) pp[tid] = pooled[b * 128 + tid] * inv;
    __syncthreads();
    {   // pooled256 = pp @ G3W + G3b  (SegMean commutes with the affine GCN3)
        float s = G3b[tid];
        #pragma unroll 8
        for (int k = 0; k < 128; ++k) s += pp[k] * G3W[k * 256 + tid];
        cat[512 + tid] = s;
    }
    __syncthreads();
    {
        float a0 = bff[tid], a1 = bff[tid + 256];
        #pragma unroll 8
        for (int k = 0; k < 768; ++k) {
            float xv = cat[k];
            a0 += xv * Wff[k * 512 + tid];
            a1 += xv * Wff[k * 512 + tid + 256];
        }
        fin[tid] = fmaxf(a0, 0.f);
        fin[tid + 256] = fmaxf(a1, 0.f);
    }
    __syncthreads();
    float z0 = 0.f, z1 = 0.f, y0 = 0.f, y1 = 0.f;
    for (int k = tid; k < 512; k += 256) {
        float f = fin[k];
        z0 += f * Wb[2 * k];
        z1 += f * Wb[2 * k + 1];
        y0 += f * Wa[2 * k];
        y1 += f * Wa[2 * k + 1];
    }
    #pragma unroll
    for (int off = 32; off > 0; off >>= 1) {
        z0 += __shfl_down(z0, off);
        z1 += __shfl_down(z1, off);
        y0 += __shfl_down(y0, off);
        y1 += __shfl_down(y1, off);
    }
    int ww = tid >> 6;
    if ((tid & 63) == 0) { rd[ww][0] = z0; rd[ww][1] = z1; rd[ww][2] = y0; rd[ww][3] = y1; }
    __syncthreads();
    if (tid == 0) {
        float Z0 = rd[0][0] + rd[1][0] + rd[2][0] + rd[3][0] + bb[0];
        float Z1 = rd[0][1] + rd[1][1] + rd[2][1] + rd[3][1] + bb[1];
        float Y0 = rd[0][2] + rd[1][2] + rd[2][2] + rd[3][2] + ba[0];
        float Y1 = rd[0][3] + rd[1][3] + rd[2][3] + rd[3][3] + ba[1];
        float m = fmaxf(Z0, Z1);
        float l = m + logf(expf(Z0 - m) + expf(Z1 - m));
        out[b * 2 + 0] = Z0 - l;
        out[b * 2 + 1] = Z1 - l;
        float m2 = fmaxf(Y0, Y1);
        float l2 = m2 + logf(expf(Y0 - m2) + expf(Y1 - m2));
        out[512 + b * 2 + 0] = Y0 - l2;
        out[512 + b * 2 + 1] = Y1 - l2;
    }
}

// scan1: block-local exclusive scan of deg (1024/block) + fused dis = rsqrt
__global__ void scan1(const int* __restrict__ in, int* __restrict__ out,
                      int* __restrict__ bsum, float* __restrict__ dis, int n) {
    __shared__ int ts[256];
    const int tid = threadIdx.x;
    const int base = blockIdx.x * 1024;
    int v[4];
    #pragma unroll
    for (int i = 0; i < 4; ++i) {
        int idx = base + tid * 4 + i;
        v[i] = (idx < n) ? in[idx] : 0;
        if (idx < NPAD) dis[idx] = rsqrtf((float)v[i] + 1.f);
    }
    ts[tid] = v[0] + v[1] + v[2] + v[3];
    __syncthreads();
    for (int off = 1; off < 256; off <<= 1) {
        int val = (tid >= off) ? ts[tid - off] : 0;
        __syncthreads();
        ts[tid] += val;
        __syncthreads();
    }
    int run = (tid == 0) ? 0 : ts[tid - 1];
    if (tid == 255) bsum[blockIdx.x] = ts[255];
    #pragma unroll
    for (int i = 0; i < 4; ++i) {
        int idx = base + tid * 4 + i;
        if (idx < n) out[idx] = run;
        run += v[i];
    }
}

// scan2: one-wave shfl scan over <=128 block sums
__global__ void scan2(int* __restrict__ bsum, int nb) {
    int l = threadIdx.x;                       // 64 threads
    int a = (l < nb) ? bsum[l] : 0;
    int b = (l + 64 < nb) ? bsum[l + 64] : 0;
    int oa = a, ob = b;
    #pragma unroll
    for (int off = 1; off < 64; off <<= 1) {
        int t = __shfl_up(a, off);
        if (l >= off) a += t;
    }
    int totA = __shfl(a, 63);
    #pragma unroll
    for (int off = 1; off < 64; off <<= 1) {
        int t = __shfl_up(b, off);
        if (l >= off) b += t;
    }
    if (l < nb) bsum[l] = a - oa;
    if (l + 64 < nb) bsum[l + 64] = totA + b - ob;
}

// ===== fused: atomic-free scatter (+rowptr materialize) AND Hs0 scale =======
#define SCAT_BLKS 6250   // edges
#define SCALE_BLKS 25000 // 100k*64/256
__global__ void scatter_scale(const int* __restrict__ srcE, const int* __restrict__ dstE,
                              const int* __restrict__ partial, const int* __restrict__ bsum,
                              const int* __restrict__ slot,
                              int* __restrict__ csr_src, int* __restrict__ rowptr,
                              const float* __restrict__ x, const float* __restrict__ dis,
                              u16* __restrict__ hs0) {
    const int bid = blockIdx.x, tid = threadIdx.x;
    if (bid < SCAT_BLKS) {
        int e = bid * 256 + tid;
        if (e <= N_NODES) rowptr[e] = (e < N_NODES) ? (partial[e] + bsum[e >> 10]) : N_EDGES;
        int d = dstE[e];
        csr_src[partial[d] + bsum[d >> 10] + slot[e]] = srcE[e];
        return;
    }
    int t = (bid - SCAT_BLKS) * 256 + tid;     // Hs0 = bf16(dis * x), 64 cols
    hs0[t] = f2bf(x[t] * dis[t >> 6]);
}

// ===== CSR aggregate bf16 (layer 1, C=64): one wave/node, G=8, 4x unroll ====
__global__ void csr_agg64(const u16* __restrict__ Hs, const int* __restrict__ rowptr,
                          const int* __restrict__ csr_src, const float* __restrict__ dis,
                          u16* __restrict__ out) {
    int node = blockIdx.x * 4 + (threadIdx.x >> 6);
    if (node >= N_NODES) return;
    int lane = threadIdx.x & 63;
    int g  = lane >> 3;               // 8 slots
    int cl = lane & 7;                // 8 ch-groups of 8
    int s0 = rowptr[node], s1 = rowptr[node + 1];
    float a[8] = {};
    if (g == 0) {
        u16x8 v = *(const u16x8*)&Hs[(size_t)node * 64 + cl * 8];
        #pragma unroll
        for (int j = 0; j < 8; ++j) a[j] = bf2f(v[j]);
    }
    int e = s0 + g;
    while (e + 24 < s1) {
        int sA = csr_src[e], sB = csr_src[e + 8];
        int sC = csr_src[e + 16], sD = csr_src[e + 24];
        u16x8 vA = *(const u16x8*)&Hs[(size_t)sA * 64 + cl * 8];
        u16x8 vB = *(const u16x8*)&Hs[(size_t)sB * 64 + cl * 8];
        u16x8 vC = *(const u16x8*)&Hs[(size_t)sC * 64 + cl * 8];
        u16x8 vD = *(const u16x8*)&Hs[(size_t)sD * 64 + cl * 8];
        #pragma unroll
        for (int j = 0; j < 8; ++j)
            a[j] += (bf2f(vA[j]) + bf2f(vB[j])) + (bf2f(vC[j]) + bf2f(vD[j]));
        e += 32;
    }
    while (e < s1) {
        int s = csr_src[e];
        u16x8 v = *(const u16x8*)&Hs[(size_t)s * 64 + cl * 8];
        #pragma unroll
        for (int j = 0; j < 8; ++j) a[j] += bf2f(v[j]);
        e += 8;
    }
    #pragma unroll
    for (int m = 8; m < 64; m <<= 1)
        #pragma unroll
        for (int j = 0; j < 8; ++j) a[j] += __shfl_xor(a[j], m);
    if (g == 0) {
        float dd = dis[node];
        u16x8 o;
        #pragma unroll
        for (int j = 0; j < 8; ++j) o[j] = f2bf(a[j] * dd);
        *(u16x8*)&out[(size_t)node * 64 + cl * 8] = o;
    }
}

// ===== CSR aggregate fp8 (layer 2, C=128): agg64 geometry on 128B fp8 rows ==
// 8 lanes/row x 16B (u8x16), G=8 slots, 2x unroll => 16 edges in flight.
__global__ void csr_agg_fp8(const u8* __restrict__ Hs, const int* __restrict__ rowptr,
                            const int* __restrict__ csr_src, const float* __restrict__ dis,
                            u16* __restrict__ out) {
    int node = blockIdx.x * 4 + (threadIdx.x >> 6);
    if (node >= N_NODES) return;
    int lane = threadIdx.x & 63;
    int g  = lane >> 3;               // 8 slots
    int cl = lane & 7;                // 8 ch-groups of 16
    int s0 = rowptr[node], s1 = rowptr[node + 1];
    float a[16] = {};
    if (g == 0) {
        u8x16 v = *(const u8x16*)&Hs[(size_t)node * 128 + cl * 16];
        #pragma unroll
        for (int j = 0; j < 16; ++j) a[j] = fp82f(v[j]);
    }
    int e = s0 + g;
    while (e + 8 < s1) {
        int sA = csr_src[e], sB = csr_src[e + 8];
        u8x16 vA = *(const u8x16*)&Hs[(size_t)sA * 128 + cl * 16];
        u8x16 vB = *(const u8x16*)&Hs[(size_t)sB * 128 + cl * 16];
        #pragma unroll
        for (int j = 0; j < 16; ++j) a[j] += fp82f(vA[j]) + fp82f(vB[j]);
        e += 16;
    }
    while (e < s1) {
        int s = csr_src[e];
        u8x16 v = *(const u8x16*)&Hs[(size_t)s * 128 + cl * 16];
        #pragma unroll
        for (int j = 0; j < 16; ++j) a[j] += fp82f(v[j]);
        e += 8;
    }
    #pragma unroll
    for (int m = 8; m < 64; m <<= 1)
        #pragma unroll
        for (int j = 0; j < 16; ++j) a[j] += __shfl_xor(a[j], m);
    if (g == 0) {
        float dd = dis[node];
        u16x8 o0, o1;
        #pragma unroll
        for (int j = 0; j < 8; ++j) { o0[j] = f2bf(a[j] * dd); o1[j] = f2bf(a[8 + j] * dd); }
        *(u16x8*)&out[(size_t)node * 128 + cl * 16] = o0;
        *(u16x8*)&out[(size_t)node * 128 + cl * 16 + 8] = o1;
    }
}

// ===== fused layer-3 fp8 agg + segment-sum pool (agg64 geometry) ============
__global__ __launch_bounds__(256) void csr_agg_pool(
        const u8* __restrict__ Hs, const int* __restrict__ rowptr,
        const int* __restrict__ csr_src, const float* __restrict__ dis,
        const int* __restrict__ batch,
        float* __restrict__ pooled, float* __restrict__ counts) {
    __shared__ float bins[2][128];
    __shared__ int cnt[2];
    const int tid = threadIdx.x;
    const int base = blockIdx.x * 16;
    if (tid < 128) { bins[0][tid] = 0.f; bins[1][tid] = 0.f; }
    if (tid < 2) cnt[tid] = 0;
    __syncthreads();
    const int lane = tid & 63;
    const int w = tid >> 6;
    const int g = lane >> 3;          // 8 slots
    const int cl = lane & 7;          // 16 channels per lane
    const int b0 = batch[base];
    #pragma unroll
    for (int i = 0; i < 4; ++i) {
        const int node = base + w * 4 + i;
        const int s0 = rowptr[node], s1 = rowptr[node + 1];
        float a[16] = {};
        if (g == 0) {
            u8x16 v = *(const u8x16*)&Hs[(size_t)node * 128 + cl * 16];
            #pragma unroll
            for (int j = 0; j < 16; ++j) a[j] = fp82f(v[j]);
        }
        int e = s0 + g;
        while (e + 8 < s1) {
            int sA = csr_src[e], sB = csr_src[e + 8];
            u8x16 vA = *(const u8x16*)&Hs[(size_t)sA * 128 + cl * 16];
            u8x16 vB = *(const u8x16*)&Hs[(size_t)sB * 128 + cl * 16];
            #pragma unroll
            for (int j = 0; j < 16; ++j) a[j] += fp82f(vA[j]) + fp82f(vB[j]);
            e += 16;
        }
        while (e < s1) {
            int s = csr_src[e];
            u8x16 v = *(const u8x16*)&Hs[(size_t)s * 128 + cl * 16];
            #pragma unroll
            for (int j = 0; j < 16; ++j) a[j] += fp82f(v[j]);
            e += 8;
        }
        #pragma unroll
        for (int m = 8; m < 64; m <<= 1)
            #pragma unroll
            for (int j = 0; j < 16; ++j) a[j] += __shfl_xor(a[j], m);
        if (g == 0) {
            int bin = (batch[node] != b0) ? 1 : 0;
            float dd = dis[node];
            #pragma unroll
            for (int j = 0; j < 16; ++j) atomicAdd(&bins[bin][cl * 16 + j], a[j] * dd);
            if (cl == 0) atomicAdd(&cnt[bin], 1);
        }
    }
    __syncthreads();
    int bin = tid >> 7, c = tid & 127;
    if (cnt[bin] > 0) atomicAdd(&pooled[(b0 + bin) * 128 + c], bins[bin][c]);
    if (tid < 2 && cnt[tid] > 0) atomicAdd(&counts[b0 + tid], (float)cnt[tid]);
}

extern "C" void kernel_launch(void* const* d_in, const int* in_sizes, int n_in,
                              void* d_out, int out_size, void* d_ws, size_t ws_size,
                              hipStream_t stream) {
    // ---- inputs (setup_inputs order) ----
    const float* video = (const float*)d_in[1];
    const float* x     = (const float*)d_in[2];
    const int*   eidx  = (const int*)d_in[3];
    const int*   batch = (const int*)d_in[4];
    // text branch + Wq/Wk are dead: seq-len-1 softmax == 1 -> attn = v.
    const float* Wv  = (const float*)d_in[7],  *bv  = (const float*)d_in[8];
    const float* Wva = (const float*)d_in[13], *bva = (const float*)d_in[14];
    const float* Wo  = (const float*)d_in[15], *bo  = (const float*)d_in[16];
    const float* Wf  = (const float*)d_in[17], *bf  = (const float*)d_in[18];
    const float* G1W = (const float*)d_in[19], *G1b = (const float*)d_in[20];
    const float* G2W = (const float*)d_in[21], *G2b = (const float*)d_in[22];
    const float* G3W = (const float*)d_in[23], *G3b = (const float*)d_in[24];
    const float* Wff = (const float*)d_in[25], *bff = (const float*)d_in[26];
    const float* Wb  = (const float*)d_in[27], *bb  = (const float*)d_in[28];
    const float* Wa  = (const float*)d_in[29], *ba  = (const float*)d_in[30];
    const int* srcE = eidx;
    const int* dstE = eidx + N_EDGES;

    // ---- workspace layout ----
    char* wsc = (char*)d_ws;
    size_t off = 0;
    auto alloc = [&](size_t bytes) { char* p = wsc + off; off += (bytes + 255) & ~(size_t)255; return p; };
    u16*   bufA    = (u16*)  alloc((size_t)NPAD * 128 * 2);   // Hs0 bf16 / Hs1,Hs2 fp8
    u16*   bufB    = (u16*)  alloc((size_t)NPAD * 128 * 2);   // agg outputs (bf16)
    float* dis     = (float*)alloc(NPAD * 4);
    int*   deg     = (int*)  alloc(NPAD * 4);                 // | contiguous
    float* pooled  = (float*)alloc((BATCH * 128 + BATCH) * 4);// | memset region
    float* counts  = pooled + BATCH * 128;
    int*   partial = (int*)  alloc(N_NODES * 4);
    int*   rowptr  = (int*)  alloc((N_NODES + 1) * 4);
    int*   slot    = (int*)  alloc((size_t)N_EDGES * 4);
    int*   csrsrc  = (int*)  alloc((size_t)N_EDGES * 4);
    int*   bsum    = (int*)  alloc(128 * 4);
    u16*   g1wt    = (u16*)  alloc(128 * 64 * 2);
    u16*   g2wt    = (u16*)  alloc(128 * 128 * 2);
    u16*   WvT     = (u16*)  alloc(512 * 512 * 2);
    u16*   WvaT    = (u16*)  alloc(512 * 512 * 2);
    u16*   WoT     = (u16*)  alloc(512 * 512 * 2);
    u16*   WfT     = (u16*)  alloc(512 * 1024 * 2);
    u16*   vidbf   = (u16*)  alloc(BATCH * 512 * 2);
    u16*   catb    = (u16*)  alloc(BATCH * 1024 * 2);         // [ta | venc]
    u16*   vattnb  = (u16*)  alloc(BATCH * 512 * 2);
    u16*   fusedb  = (u16*)  alloc(BATCH * 512 * 2);

    const int NB = (N_NODES + 1023) / 1024;   // 98

    // ---- single memset over deg + pooled + counts (contiguous) ----
    hipMemsetAsync(deg, 0, NPAD * 4 + (BATCH * 128 + BATCH) * 4, stream);

    // ---- fused: deg/slot histogram + weight transposes + video cast ----
    prep_deg<<<DEG_BLKS + 5728, 256, 0, stream>>>(dstE, deg, slot,
        G1W, g1wt, G2W, g2wt, Wv, WvT, Wva, WvaT, Wo, WoT, Wf, WfT, video, vidbf);

    // ---- scans; fused scatter (rowptr inside) + Hs0 scale ----
    scan1<<<NB, 256, 0, stream>>>(deg, partial, bsum, dis, N_NODES);
    scan2<<<1, 64, 0, stream>>>(bsum, NB);
    scatter_scale<<<SCAT_BLKS + SCALE_BLKS, 256, 0, stream>>>(
        srcE, dstE, partial, bsum, slot, csrsrc, rowptr, x, dis, bufA);

    // ---- front-end on MFMA, 64x64 tiles (attn collapses: attn = v) ----
    dim3 fe512(8, 4);     // N=512, M=256
    gemm64<1><<<fe512, 256, 0, stream>>>(vidbf, WvT, bv, catb + 512, 512, 512, 1024);
    gemm64<0><<<fe512, 256, 0, stream>>>(catb + 512, WvaT, bva, vattnb, 512, 1024, 512);
    gemm64<0><<<fe512, 256, 0, stream>>>(vattnb, WoT, bo, catb, 512, 512, 1024);
    gemm64<1><<<fe512, 256, 0, stream>>>(catb, WfT, bf, fusedb, 1024, 1024, 512);

    // ---- GCN stack: aggregate-first; fp8 gather rows for layers 2+3 ----
    csr_agg64<<<(N_NODES + 3) / 4, 256, 0, stream>>>(bufA, rowptr, csrsrc, dis, bufB);
    gemm_mfma<64, 2, 1, 1><<<dim3(1, NPAD / 128), 256, 0, stream>>>(
        bufB, g1wt, G1b, dis, bufA, 128);                      // Hs1 -> fp8
    csr_agg_fp8<<<(N_NODES + 3) / 4, 256, 0, stream>>>((const u8*)bufA, rowptr, csrsrc, dis, bufB);
    gemm_mfma<128, 2, 1, 1><<<dim3(1, NPAD / 128), 256, 0, stream>>>(
        bufB, g2wt, G2b, dis, bufA, 128);                      // Hs2 -> fp8
    // layer-3 agg fused with segment pooling (GEMM3 deferred to final_fused)
    csr_agg_pool<<<N_NODES / 16, 256, 0, stream>>>((const u8*)bufA, rowptr, csrsrc, dis,
                                                   batch, pooled, counts);

    // ---- fused tail: mean + G3W matvec + concat + Wff + heads ----
    final_fused<<<BATCH, 256, 0, stream>>>(fusedb, pooled, counts, G3W, G3b,
                                           Wff, bff, Wb, bb, Wa, ba, (float*)d_out);
}

// Round 11
// 427.452 us; speedup vs baseline: 1.0907x; 1.0907x over previous
//
#include <hip/hip_runtime.h>
#include <hip/hip_bf16.h>
#include <hip/hip_fp8.h>

#define N_NODES 100000
#define NPAD    100096          // 782 * 128
#define N_EDGES 1600000
#define BATCH   256
#define HDIM    512

typedef unsigned short u16;
typedef unsigned char  u8;
typedef __attribute__((ext_vector_type(8))) short bf16x8;
typedef __attribute__((ext_vector_type(8))) unsigned short u16x8;
typedef __attribute__((ext_vector_type(8))) unsigned char u8x8;
typedef __attribute__((ext_vector_type(4))) float f32x4;

__device__ __forceinline__ float bf2f(u16 u) {
    union { unsigned i; float f; } v; v.i = ((unsigned)u) << 16; return v.f;
}
__device__ __forceinline__ u16 f2bf(float f) {
    __hip_bfloat16 h = __float2bfloat16(f);
    return *reinterpret_cast<u16*>(&h);
}
__device__ __forceinline__ u8 f2fp8(float f) {
    __hip_fp8_e4m3 q(f); return (u8)q.__x;
}
__device__ __forceinline__ float fp82f(u8 b) {
    __hip_fp8_e4m3 q; q.__x = (__hip_fp8_storage_t)b; return (float)q;
}

// ============ MFMA GEMM (node path): C = act(A[M,K]@W) , K<=128, 1 stage =====
// A: [M][K] bf16. Wt: [N][K] bf16. 128x128 tile, 4 waves 2x2, 4x4 frags of
// 16x16x32. LDS via global_load_lds w=16, pre-swizzled source (rule 21).
// ACT: 0 none, 2 elu. SCALE: dis[row]. F8: store e4m3 fp8 (else bf16).
template<int K, int ACT, int SCALE, int F8>
__global__ __launch_bounds__(256) void gemm_mfma(
        const u16* __restrict__ A, const u16* __restrict__ Wt,
        const float* __restrict__ bias, const float* __restrict__ dis,
        void* __restrict__ Cv, int N) {
    constexpr int RB = K * 2;                 // row bytes
    __shared__ u16 As[128 * K];
    __shared__ u16 Bs[128 * K];
    const int tid  = threadIdx.x;
    const int lane = tid & 63;
    const int w    = tid >> 6;
    const int wr   = w >> 1, wc = w & 1;
    const int row0 = blockIdx.y * 128;
    const int col0 = blockIdx.x * 128;

    constexpr int WB     = 128 * RB / 4;
    constexpr int PASSES = WB / 1024;
    const size_t Abase = (size_t)row0 * K;
    const size_t Bbase = (size_t)col0 * K;
    #pragma unroll
    for (int p = 0; p < PASSES; ++p) {
        int Lb  = w * WB + p * 1024;
        int L   = Lb + lane * 16;
        int row = L / RB;
        int cb  = L % RB;
        int scb = cb ^ ((row & 7) << 4);
        const u16* ga = A  + Abase + (size_t)row * K + (scb >> 1);
        const u16* gb = Wt + Bbase + (size_t)row * K + (scb >> 1);
        __builtin_amdgcn_global_load_lds((const __attribute__((address_space(1))) void*)ga,
            (__attribute__((address_space(3))) void*)&As[Lb >> 1], 16, 0, 0);
        __builtin_amdgcn_global_load_lds((const __attribute__((address_space(1))) void*)gb,
            (__attribute__((address_space(3))) void*)&Bs[Lb >> 1], 16, 0, 0);
    }
    asm volatile("s_waitcnt vmcnt(0)" ::: "memory");
    __syncthreads();

    const int rl = lane & 15;
    const int kg = lane >> 4;
    f32x4 acc[4][4] = {};
    #pragma unroll
    for (int s = 0; s < K / 32; ++s) {
        bf16x8 af[4], bg[4];
        #pragma unroll
        for (int m = 0; m < 4; ++m) {
            int row = wr * 64 + m * 16 + rl;
            int cb  = s * 64 + kg * 16;
            int scb = cb ^ ((row & 7) << 4);
            af[m] = *(const bf16x8*)&As[(row * RB + scb) >> 1];
        }
        #pragma unroll
        for (int n = 0; n < 4; ++n) {
            int row = wc * 64 + n * 16 + rl;
            int cb  = s * 64 + kg * 16;
            int scb = cb ^ ((row & 7) << 4);
            bg[n] = *(const bf16x8*)&Bs[(row * RB + scb) >> 1];
        }
        #pragma unroll
        for (int m = 0; m < 4; ++m)
            #pragma unroll
            for (int n = 0; n < 4; ++n)
                acc[m][n] = __builtin_amdgcn_mfma_f32_16x16x32_bf16(af[m], bg[n], acc[m][n], 0, 0, 0);
    }

    #pragma unroll
    for (int m = 0; m < 4; ++m) {
        #pragma unroll
        for (int r = 0; r < 4; ++r) {
            int grow = row0 + wr * 64 + m * 16 + kg * 4 + r;
            float ds = SCALE ? dis[grow] : 1.f;
            #pragma unroll
            for (int n = 0; n < 4; ++n) {
                int gcol = col0 + wc * 64 + n * 16 + rl;
                float v = acc[m][n][r] + bias[gcol];
                if (ACT == 2) v = v > 0.f ? v : expm1f(v);
                v *= ds;
                if (F8) ((u8*)Cv)[(size_t)grow * N + gcol] = f2fp8(v);
                else    ((u16*)Cv)[(size_t)grow * N + gcol] = f2bf(v);
            }
        }
    }
}

// ======== MFMA GEMM (front-end): 64x64 tile, K-loop BK=64, runtime lda/ldc ==
template<int ACT>
__global__ __launch_bounds__(256) void gemm64(
        const u16* __restrict__ A, const u16* __restrict__ Wt,
        const float* __restrict__ bias, u16* __restrict__ C,
        int K, int lda, int ldc) {
    __shared__ u16 As[64 * 64];
    __shared__ u16 Bs[64 * 64];
    const int tid  = threadIdx.x;
    const int lane = tid & 63;
    const int w    = tid >> 6;
    const int wr   = w >> 1, wc = w & 1;
    const int row0 = blockIdx.y * 64;
    const int col0 = blockIdx.x * 64;
    const int rl = lane & 15;
    const int kg = lane >> 4;
    f32x4 acc[2][2] = {};

    for (int k0 = 0; k0 < K; k0 += 64) {
        #pragma unroll
        for (int p = 0; p < 2; ++p) {
            int Lb  = w * 2048 + p * 1024;
            int L   = Lb + lane * 16;
            int row = L >> 7;
            int cb  = L & 127;
            int scb = cb ^ ((row & 7) << 4);
            const u16* ga = A  + (size_t)(row0 + row) * lda + k0 + (scb >> 1);
            const u16* gb = Wt + (size_t)(col0 + row) * K   + k0 + (scb >> 1);
            __builtin_amdgcn_global_load_lds((const __attribute__((address_space(1))) void*)ga,
                (__attribute__((address_space(3))) void*)&As[Lb >> 1], 16, 0, 0);
            __builtin_amdgcn_global_load_lds((const __attribute__((address_space(1))) void*)gb,
                (__attribute__((address_space(3))) void*)&Bs[Lb >> 1], 16, 0, 0);
        }
        asm volatile("s_waitcnt vmcnt(0)" ::: "memory");
        __syncthreads();
        #pragma unroll
        for (int s = 0; s < 2; ++s) {
            bf16x8 af[2], bg[2];
            #pragma unroll
            for (int m = 0; m < 2; ++m) {
                int row = wr * 32 + m * 16 + rl;
                int cb  = s * 64 + kg * 16;
                int scb = cb ^ ((row & 7) << 4);
                af[m] = *(const bf16x8*)&As[(row * 128 + scb) >> 1];
            }
            #pragma unroll
            for (int n = 0; n < 2; ++n) {
                int row = wc * 32 + n * 16 + rl;
                int cb  = s * 64 + kg * 16;
                int scb = cb ^ ((row & 7) << 4);
                bg[n] = *(const bf16x8*)&Bs[(row * 128 + scb) >> 1];
            }
            #pragma unroll
            for (int m = 0; m < 2; ++m)
                #pragma unroll
                for (int n = 0; n < 2; ++n)
                    acc[m][n] = __builtin_amdgcn_mfma_f32_16x16x32_bf16(af[m], bg[n], acc[m][n], 0, 0, 0);
        }
        __syncthreads();
    }

    #pragma unroll
    for (int m = 0; m < 2; ++m) {
        #pragma unroll
        for (int r = 0; r < 4; ++r) {
            int grow = row0 + wr * 32 + m * 16 + kg * 4 + r;
            #pragma unroll
            for (int n = 0; n < 2; ++n) {
                int gcol = col0 + wc * 32 + n * 16 + rl;
                float v = acc[m][n][r] + bias[gcol];
                if (ACT == 1) v = fmaxf(v, 0.f);
                C[(size_t)grow * ldc + gcol] = f2bf(v);
            }
        }
    }
}

// ===== fused prep+deg: histogram/slot pass AND weight transposes + video ====
template<int K, int N>
__device__ __forceinline__ void tw(const float* __restrict__ W, u16* __restrict__ Wt, int t) {
    int n = t / K, k = t - n * K;
    Wt[t] = f2bf(W[(size_t)k * N + n]);
}

#define DEG_BLKS 6250   // 6250*256 = 1.6M edges

__global__ void prep_deg(const int* __restrict__ dstE, int* __restrict__ deg,
                         int* __restrict__ slot,
                         const float* __restrict__ G1W, u16* __restrict__ g1wt,
                         const float* __restrict__ G2W, u16* __restrict__ g2wt,
                         const float* __restrict__ Wv,  u16* __restrict__ WvT,
                         const float* __restrict__ Wva, u16* __restrict__ WvaT,
                         const float* __restrict__ Wo,  u16* __restrict__ WoT,
                         const float* __restrict__ Wf,  u16* __restrict__ WfT,
                         const float* __restrict__ video, u16* __restrict__ vidbf) {
    int bid = blockIdx.x;
    const int tid = threadIdx.x;
    if (bid < DEG_BLKS) {
        int e = bid * 256 + tid;
        slot[e] = atomicAdd(&deg[dstE[e]], 1);
        return;
    }
    bid -= DEG_BLKS;
    if (bid < 32)        { tw<64, 128>  (G1W, g1wt, bid * 256 + tid); }
    else if (bid < 96)   { tw<128, 128> (G2W, g2wt, (bid - 32) * 256 + tid); }
    else if (bid < 1120) { tw<512, 512> (Wv,  WvT,  (bid - 96) * 256 + tid); }
    else if (bid < 2144) { tw<512, 512> (Wva, WvaT, (bid - 1120) * 256 + tid); }
    else if (bid < 3168) { tw<512, 512> (Wo,  WoT,  (bid - 2144) * 256 + tid); }
    else if (bid < 5216) { tw<1024, 512>(Wf,  WfT,  (bid - 3168) * 256 + tid); }
    else { int t = (bid - 5216) * 256 + tid; vidbf[t] = f2bf(video[t]); }
}

// == fused tail: pooled256 = (pool/cnt)@G3W+b3; final = relu([f|p]@Wff); heads
__global__ void final_fused(const u16* __restrict__ fusedb,
                            const float* __restrict__ pooled, const float* __restrict__ counts,
                            const float* __restrict__ G3W, const float* __restrict__ G3b,
                            const float* __restrict__ Wff, const float* __restrict__ bff,
                            const float* __restrict__ Wb,  const float* __restrict__ bb,
                            const float* __restrict__ Wa,  const float* __restrict__ ba,
                            float* __restrict__ out) {
    __shared__ float cat[768], fin[512], pp[128];
    __shared__ float rd[4][4];
    const int b = blockIdx.x, tid = threadIdx.x;
    cat[tid] = bf2f(fusedb[b * 512 + tid]);
    cat[tid + 256] = bf2f(fusedb[b * 512 + 256 + tid]);
    float inv = 1.f / counts[b];
    if (tid < 128) pp[tid] = pooled[b * 128 + tid] * inv;
    __syncthreads();
    {   // pooled256 = pp @ G3W + G3b  (SegMean commutes with the affine GCN3)
        float s = G3b[tid];
        #pragma unroll 8
        for (int k = 0; k < 128; ++k) s += pp[k] * G3W[k * 256 + tid];
        cat[512 + tid] = s;
    }
    __syncthreads();
    {
        float a0 = bff[tid], a1 = bff[tid + 256];
        #pragma unroll 8
        for (int k = 0; k < 768; ++k) {
            float xv = cat[k];
            a0 += xv * Wff[k * 512 + tid];
            a1 += xv * Wff[k * 512 + tid + 256];
        }
        fin[tid] = fmaxf(a0, 0.f);
        fin[tid + 256] = fmaxf(a1, 0.f);
    }
    __syncthreads();
    float z0 = 0.f, z1 = 0.f, y0 = 0.f, y1 = 0.f;
    for (int k = tid; k < 512; k += 256) {
        float f = fin[k];
        z0 += f * Wb[2 * k];
        z1 += f * Wb[2 * k + 1];
        y0 += f * Wa[2 * k];
        y1 += f * Wa[2 * k + 1];
    }
    #pragma unroll
    for (int off = 32; off > 0; off >>= 1) {
        z0 += __shfl_down(z0, off);
        z1 += __shfl_down(z1, off);
        y0 += __shfl_down(y0, off);
        y1 += __shfl_down(y1, off);
    }
    int ww = tid >> 6;
    if ((tid & 63) == 0) { rd[ww][0] = z0; rd[ww][1] = z1; rd[ww][2] = y0; rd[ww][3] = y1; }
    __syncthreads();
    if (tid == 0) {
        float Z0 = rd[0][0] + rd[1][0] + rd[2][0] + rd[3][0] + bb[0];
        float Z1 = rd[0][1] + rd[1][1] + rd[2][1] + rd[3][1] + bb[1];
        float Y0 = rd[0][2] + rd[1][2] + rd[2][2] + rd[3][2] + ba[0];
        float Y1 = rd[0][3] + rd[1][3] + rd[2][3] + rd[3][3] + ba[1];
        float m = fmaxf(Z0, Z1);
        float l = m + logf(expf(Z0 - m) + expf(Z1 - m));
        out[b * 2 + 0] = Z0 - l;
        out[b * 2 + 1] = Z1 - l;
        float m2 = fmaxf(Y0, Y1);
        float l2 = m2 + logf(expf(Y0 - m2) + expf(Y1 - m2));
        out[512 + b * 2 + 0] = Y0 - l2;
        out[512 + b * 2 + 1] = Y1 - l2;
    }
}

// scan1: block-local exclusive scan of deg (1024/block) + fused dis = rsqrt
__global__ void scan1(const int* __restrict__ in, int* __restrict__ out,
                      int* __restrict__ bsum, float* __restrict__ dis, int n) {
    __shared__ int ts[256];
    const int tid = threadIdx.x;
    const int base = blockIdx.x * 1024;
    int v[4];
    #pragma unroll
    for (int i = 0; i < 4; ++i) {
        int idx = base + tid * 4 + i;
        v[i] = (idx < n) ? in[idx] : 0;
        if (idx < NPAD) dis[idx] = rsqrtf((float)v[i] + 1.f);
    }
    ts[tid] = v[0] + v[1] + v[2] + v[3];
    __syncthreads();
    for (int off = 1; off < 256; off <<= 1) {
        int val = (tid >= off) ? ts[tid - off] : 0;
        __syncthreads();
        ts[tid] += val;
        __syncthreads();
    }
    int run = (tid == 0) ? 0 : ts[tid - 1];
    if (tid == 255) bsum[blockIdx.x] = ts[255];
    #pragma unroll
    for (int i = 0; i < 4; ++i) {
        int idx = base + tid * 4 + i;
        if (idx < n) out[idx] = run;
        run += v[i];
    }
}

// scan2: one-wave shfl scan over <=128 block sums
__global__ void scan2(int* __restrict__ bsum, int nb) {
    int l = threadIdx.x;                       // 64 threads
    int a = (l < nb) ? bsum[l] : 0;
    int b = (l + 64 < nb) ? bsum[l + 64] : 0;
    int oa = a, ob = b;
    #pragma unroll
    for (int off = 1; off < 64; off <<= 1) {
        int t = __shfl_up(a, off);
        if (l >= off) a += t;
    }
    int totA = __shfl(a, 63);
    #pragma unroll
    for (int off = 1; off < 64; off <<= 1) {
        int t = __shfl_up(b, off);
        if (l >= off) b += t;
    }
    if (l < nb) bsum[l] = a - oa;
    if (l + 64 < nb) bsum[l + 64] = totA + b - ob;
}

// ===== fused: atomic-free scatter (+rowptr materialize) AND Hs0 scale =======
// csr_sd[pos] = {src, dst}  (8B to one line: same WRITE traffic as 4B).
#define SCAT_BLKS 6250   // edges
#define SCALE_BLKS 25000 // 100k*64/256
__global__ void scatter_scale(const int* __restrict__ srcE, const int* __restrict__ dstE,
                              const int* __restrict__ partial, const int* __restrict__ bsum,
                              const int* __restrict__ slot,
                              int2* __restrict__ csr_sd, int* __restrict__ rowptr,
                              const float* __restrict__ x, const float* __restrict__ dis,
                              u16* __restrict__ hs0) {
    const int bid = blockIdx.x, tid = threadIdx.x;
    if (bid < SCAT_BLKS) {
        int e = bid * 256 + tid;
        if (e <= N_NODES) rowptr[e] = (e < N_NODES) ? (partial[e] + bsum[e >> 10]) : N_EDGES;
        int d = dstE[e];
        csr_sd[partial[d] + bsum[d >> 10] + slot[e]] = make_int2(srcE[e], d);
        return;
    }
    int t = (bid - SCAT_BLKS) * 256 + tid;     // Hs0 = bf16(dis * x), 64 cols
    hs0[t] = f2bf(x[t] * dis[t >> 6]);
}

// ===== CSR aggregate bf16 (layer 1, C=64): one wave/node, G=8, 4x unroll ====
__global__ void csr_agg64(const u16* __restrict__ Hs, const int* __restrict__ rowptr,
                          const int2* __restrict__ csr_sd, const float* __restrict__ dis,
                          u16* __restrict__ out) {
    int node = blockIdx.x * 4 + (threadIdx.x >> 6);
    if (node >= N_NODES) return;
    int lane = threadIdx.x & 63;
    int g  = lane >> 3;               // 8 slots
    int cl = lane & 7;                // 8 ch-groups of 8
    int s0 = rowptr[node], s1 = rowptr[node + 1];
    float a[8] = {};
    if (g == 0) {
        u16x8 v = *(const u16x8*)&Hs[(size_t)node * 64 + cl * 8];
        #pragma unroll
        for (int j = 0; j < 8; ++j) a[j] = bf2f(v[j]);
    }
    int e = s0 + g;
    while (e + 24 < s1) {
        int sA = csr_sd[e].x, sB = csr_sd[e + 8].x;
        int sC = csr_sd[e + 16].x, sD = csr_sd[e + 24].x;
        u16x8 vA = *(const u16x8*)&Hs[(size_t)sA * 64 + cl * 8];
        u16x8 vB = *(const u16x8*)&Hs[(size_t)sB * 64 + cl * 8];
        u16x8 vC = *(const u16x8*)&Hs[(size_t)sC * 64 + cl * 8];
        u16x8 vD = *(const u16x8*)&Hs[(size_t)sD * 64 + cl * 8];
        #pragma unroll
        for (int j = 0; j < 8; ++j)
            a[j] += (bf2f(vA[j]) + bf2f(vB[j])) + (bf2f(vC[j]) + bf2f(vD[j]));
        e += 32;
    }
    while (e < s1) {
        int s = csr_sd[e].x;
        u16x8 v = *(const u16x8*)&Hs[(size_t)s * 64 + cl * 8];
        #pragma unroll
        for (int j = 0; j < 8; ++j) a[j] += bf2f(v[j]);
        e += 8;
    }
    #pragma unroll
    for (int m = 8; m < 64; m <<= 1)
        #pragma unroll
        for (int j = 0; j < 8; ++j) a[j] += __shfl_xor(a[j], m);
    if (g == 0) {
        float dd = dis[node];
        u16x8 o;
        #pragma unroll
        for (int j = 0; j < 8; ++j) o[j] = f2bf(a[j] * dd);
        *(u16x8*)&out[(size_t)node * 64 + cl * 8] = o;
    }
}

// ===== CSR aggregate fp8 (layer 2, C=128): round-9 geometry (G=4, u8x8) =====
__global__ void csr_agg_fp8(const u8* __restrict__ Hs, const int* __restrict__ rowptr,
                            const int2* __restrict__ csr_sd, const float* __restrict__ dis,
                            u16* __restrict__ out) {
    int node = blockIdx.x * 4 + (threadIdx.x >> 6);
    if (node >= N_NODES) return;
    int lane = threadIdx.x & 63;
    int g  = lane >> 4;               // 4 slots
    int cl = lane & 15;               // 16 ch-groups of 8
    int s0 = rowptr[node], s1 = rowptr[node + 1];
    float a[8] = {};
    if (g == 0) {
        u8x8 v = *(const u8x8*)&Hs[(size_t)node * 128 + cl * 8];
        #pragma unroll
        for (int j = 0; j < 8; ++j) a[j] = fp82f(v[j]);
    }
    int e = s0 + g;
    while (e + 12 < s1) {
        int sA = csr_sd[e].x, sB = csr_sd[e + 4].x;
        int sC = csr_sd[e + 8].x, sD = csr_sd[e + 12].x;
        u8x8 vA = *(const u8x8*)&Hs[(size_t)sA * 128 + cl * 8];
        u8x8 vB = *(const u8x8*)&Hs[(size_t)sB * 128 + cl * 8];
        u8x8 vC = *(const u8x8*)&Hs[(size_t)sC * 128 + cl * 8];
        u8x8 vD = *(const u8x8*)&Hs[(size_t)sD * 128 + cl * 8];
        #pragma unroll
        for (int j = 0; j < 8; ++j)
            a[j] += (fp82f(vA[j]) + fp82f(vB[j])) + (fp82f(vC[j]) + fp82f(vD[j]));
        e += 16;
    }
    while (e < s1) {
        int s = csr_sd[e].x;
        u8x8 v = *(const u8x8*)&Hs[(size_t)s * 128 + cl * 8];
        #pragma unroll
        for (int j = 0; j < 8; ++j) a[j] += fp82f(v[j]);
        e += 4;
    }
    #pragma unroll
    for (int m = 16; m < 64; m <<= 1)
        #pragma unroll
        for (int j = 0; j < 8; ++j) a[j] += __shfl_xor(a[j], m);
    if (g == 0) {
        float dd = dis[node];
        u16x8 o;
        #pragma unroll
        for (int j = 0; j < 8; ++j) o[j] = f2bf(a[j] * dd);
        *(u16x8*)&out[(size_t)node * 128 + cl * 8] = o;
    }
}

// ===== edge-parallel layer-3 pool: pooled[b] = self + edge terms ===========
// Edge blocks: chunk of 1024 CSR-ordered edges (batch[dst] monotone, <=2 bins
// per chunk). 16 slots/block (16 lanes x u8x8, round-9 geometry), uniform
// strided loop — no rowptr, no per-node serialization.
// Self blocks: stream 256 nodes, pooled[b] += dis[d]*Hs2[d]; counts too.
#define PE_BLKS 1563    // ceil(1.6M / 1024)
#define PS_BLKS 391     // ceil(100k / 256)
__global__ __launch_bounds__(256) void pool_fused(
        const u8* __restrict__ Hs, const int2* __restrict__ csr_sd,
        const float* __restrict__ dis, const int* __restrict__ batch,
        float* __restrict__ pooled, float* __restrict__ counts) {
    __shared__ float bins[2][128];
    __shared__ int b0s;
    const int tid = threadIdx.x;
    const int bid = blockIdx.x;
    if (tid < 128) { bins[0][tid] = 0.f; bins[1][tid] = 0.f; }
    if (bid < PE_BLKS) {
        const int base = bid * 1024;
        const int end  = min(base + 1024, N_EDGES);
        if (tid == 0) b0s = batch[csr_sd[base].y];
        __syncthreads();
        const int b0 = b0s;
        const int lane = tid & 63, w = tid >> 6;
        const int slot = w * 4 + (lane >> 4);   // 16 slots
        const int cl = lane & 15;               // 8 channels each
        float a[8] = {};
        int bcur = b0;
        for (int e = base + slot; e < end; e += 16) {
            int2 sd = csr_sd[e];
            float dd = dis[sd.y];
            int b = batch[sd.y];
            if (b != bcur) {
                if (bcur - b0 < 2) {
                    #pragma unroll
                    for (int j = 0; j < 8; ++j) atomicAdd(&bins[bcur - b0][cl * 8 + j], a[j]);
                } else {
                    #pragma unroll
                    for (int j = 0; j < 8; ++j) atomicAdd(&pooled[bcur * 128 + cl * 8 + j], a[j]);
                }
                #pragma unroll
                for (int j = 0; j < 8; ++j) a[j] = 0.f;
                bcur = b;
            }
            u8x8 v = *(const u8x8*)&Hs[(size_t)sd.x * 128 + cl * 8];
            #pragma unroll
            for (int j = 0; j < 8; ++j) a[j] += fp82f(v[j]) * dd;
        }
        if (bcur - b0 < 2) {
            #pragma unroll
            for (int j = 0; j < 8; ++j) atomicAdd(&bins[bcur - b0][cl * 8 + j], a[j]);
        } else {
            #pragma unroll
            for (int j = 0; j < 8; ++j) atomicAdd(&pooled[bcur * 128 + cl * 8 + j], a[j]);
        }
        __syncthreads();
        int bin = tid >> 7, c = tid & 127;
        if (b0 + bin < BATCH) atomicAdd(&pooled[(b0 + bin) * 128 + c], bins[bin][c]);
    } else {
        const int base = (bid - PE_BLKS) * 256;
        const int end  = min(base + 256, N_NODES);
        if (tid == 0) b0s = batch[base];
        __syncthreads();
        const int b0 = b0s;
        const int c = tid & 127, h = tid >> 7;
        float a = 0.f; int bcur = b0; int cnt = 0;
        for (int n = base + h; n < end; n += 2) {
            int b = batch[n];
            if (b != bcur) {
                atomicAdd(&bins[bcur - b0][c], a);
                if (c == 0) atomicAdd(&counts[bcur], (float)cnt);
                a = 0.f; cnt = 0; bcur = b;
            }
            a += fp82f(Hs[(size_t)n * 128 + c]) * dis[n];
            cnt++;
        }
        atomicAdd(&bins[bcur - b0][c], a);
        if (c == 0) atomicAdd(&counts[bcur], (float)cnt);
        __syncthreads();
        int bin = tid >> 7, cc = tid & 127;
        if (b0 + bin < BATCH) atomicAdd(&pooled[(b0 + bin) * 128 + cc], bins[bin][cc]);
    }
}

extern "C" void kernel_launch(void* const* d_in, const int* in_sizes, int n_in,
                              void* d_out, int out_size, void* d_ws, size_t ws_size,
                              hipStream_t stream) {
    // ---- inputs (setup_inputs order) ----
    const float* video = (const float*)d_in[1];
    const float* x     = (const float*)d_in[2];
    const int*   eidx  = (const int*)d_in[3];
    const int*   batch = (const int*)d_in[4];
    // text branch + Wq/Wk are dead: seq-len-1 softmax == 1 -> attn = v.
    const float* Wv  = (const float*)d_in[7],  *bv  = (const float*)d_in[8];
    const float* Wva = (const float*)d_in[13], *bva = (const float*)d_in[14];
    const float* Wo  = (const float*)d_in[15], *bo  = (const float*)d_in[16];
    const float* Wf  = (const float*)d_in[17], *bf  = (const float*)d_in[18];
    const float* G1W = (const float*)d_in[19], *G1b = (const float*)d_in[20];
    const float* G2W = (const float*)d_in[21], *G2b = (const float*)d_in[22];
    const float* G3W = (const float*)d_in[23], *G3b = (const float*)d_in[24];
    const float* Wff = (const float*)d_in[25], *bff = (const float*)d_in[26];
    const float* Wb  = (const float*)d_in[27], *bb  = (const float*)d_in[28];
    const float* Wa  = (const float*)d_in[29], *ba  = (const float*)d_in[30];
    const int* srcE = eidx;
    const int* dstE = eidx + N_EDGES;

    // ---- workspace layout ----
    char* wsc = (char*)d_ws;
    size_t off = 0;
    auto alloc = [&](size_t bytes) { char* p = wsc + off; off += (bytes + 255) & ~(size_t)255; return p; };
    u16*   bufA    = (u16*)  alloc((size_t)NPAD * 128 * 2);   // Hs0 bf16 / Hs1,Hs2 fp8
    u16*   bufB    = (u16*)  alloc((size_t)NPAD * 128 * 2);   // agg outputs (bf16)
    float* dis     = (float*)alloc(NPAD * 4);
    int*   deg     = (int*)  alloc(NPAD * 4);                 // | contiguous
    float* pooled  = (float*)alloc((BATCH * 128 + BATCH) * 4);// | memset region
    float* counts  = pooled + BATCH * 128;
    int*   partial = (int*)  alloc(N_NODES * 4);
    int*   rowptr  = (int*)  alloc((N_NODES + 1) * 4);
    int*   slot    = (int*)  alloc((size_t)N_EDGES * 4);
    int2*  csr_sd  = (int2*) alloc((size_t)N_EDGES * 8);
    int*   bsum    = (int*)  alloc(128 * 4);
    u16*   g1wt    = (u16*)  alloc(128 * 64 * 2);
    u16*   g2wt    = (u16*)  alloc(128 * 128 * 2);
    u16*   WvT     = (u16*)  alloc(512 * 512 * 2);
    u16*   WvaT    = (u16*)  alloc(512 * 512 * 2);
    u16*   WoT     = (u16*)  alloc(512 * 512 * 2);
    u16*   WfT     = (u16*)  alloc(512 * 1024 * 2);
    u16*   vidbf   = (u16*)  alloc(BATCH * 512 * 2);
    u16*   catb    = (u16*)  alloc(BATCH * 1024 * 2);         // [ta | venc]
    u16*   vattnb  = (u16*)  alloc(BATCH * 512 * 2);
    u16*   fusedb  = (u16*)  alloc(BATCH * 512 * 2);

    const int NB = (N_NODES + 1023) / 1024;   // 98

    // ---- single memset over deg + pooled + counts (contiguous) ----
    hipMemsetAsync(deg, 0, NPAD * 4 + (BATCH * 128 + BATCH) * 4, stream);

    // ---- fused: deg/slot histogram + weight transposes + video cast ----
    prep_deg<<<DEG_BLKS + 5728, 256, 0, stream>>>(dstE, deg, slot,
        G1W, g1wt, G2W, g2wt, Wv, WvT, Wva, WvaT, Wo, WoT, Wf, WfT, video, vidbf);

    // ---- scans; fused scatter (rowptr inside) + Hs0 scale ----
    scan1<<<NB, 256, 0, stream>>>(deg, partial, bsum, dis, N_NODES);
    scan2<<<1, 64, 0, stream>>>(bsum, NB);
    scatter_scale<<<SCAT_BLKS + SCALE_BLKS, 256, 0, stream>>>(
        srcE, dstE, partial, bsum, slot, csr_sd, rowptr, x, dis, bufA);

    // ---- front-end on MFMA, 64x64 tiles (attn collapses: attn = v) ----
    dim3 fe512(8, 4);     // N=512, M=256
    gemm64<1><<<fe512, 256, 0, stream>>>(vidbf, WvT, bv, catb + 512, 512, 512, 1024);
    gemm64<0><<<fe512, 256, 0, stream>>>(catb + 512, WvaT, bva, vattnb, 512, 1024, 512);
    gemm64<0><<<fe512, 256, 0, stream>>>(vattnb, WoT, bo, catb, 512, 512, 1024);
    gemm64<1><<<fe512, 256, 0, stream>>>(catb, WfT, bf, fusedb, 1024, 1024, 512);

    // ---- GCN stack: aggregate-first; fp8 gather rows for layers 2+3 ----
    csr_agg64<<<(N_NODES + 3) / 4, 256, 0, stream>>>(bufA, rowptr, csr_sd, dis, bufB);
    gemm_mfma<64, 2, 1, 1><<<dim3(1, NPAD / 128), 256, 0, stream>>>(
        bufB, g1wt, G1b, dis, bufA, 128);                      // Hs1 -> fp8
    csr_agg_fp8<<<(N_NODES + 3) / 4, 256, 0, stream>>>((const u8*)bufA, rowptr, csr_sd, dis, bufB);
    gemm_mfma<128, 2, 1, 1><<<dim3(1, NPAD / 128), 256, 0, stream>>>(
        bufB, g2wt, G2b, dis, bufA, 128);                      // Hs2 -> fp8
    // layer-3: edge-parallel pool (no rowptr; GEMM3 deferred to final_fused)
    pool_fused<<<PE_BLKS + PS_BLKS, 256, 0, stream>>>((const u8*)bufA, csr_sd, dis,
                                                      batch, pooled, counts);

    // ---- fused tail: mean + G3W matvec + concat + Wff + heads ----
    final_fused<<<BATCH, 256, 0, stream>>>(fusedb, pooled, counts, G3W, G3b,
                                           Wff, bff, Wb, bb, Wa, ba, (float*)d_out);
}